// Round 1
// 174.782 us; speedup vs baseline: 1.0716x; 1.0716x over previous
//
#include <hip/hip_runtime.h>

// PINN fused: u, du/dx0, d2u/dx0^2 of tanh-MLP (2->256->256->256->1), fp32 in/out.
// Round 7: attack the LDS-read pipe (round-6 binding pipe: 8 waves x full 48KB
// A-tile re-read/layer = ~85us LDS occupancy vs 50us MFMA floor).
//   - 4 waves x nt=4 strips x mt=2 (256 thr): halves per-block LDS reads.
//     acc[3][4][2] f32x4 = 96 VGPR; __launch_bounds__(256,2) so no spill.
//   - XOR-swizzled A-tile (granule ^= row&7, LDK=256 no pad, 48KB): every
//     in-order 8-lane group covers all 8 bank-quads on reads AND writes
//     (layer-1 sample index remapped so m&7 == lane&7).
//   - weight frags re-laid per-kc contiguous: 4 strip loads = 1 vaddr + imm
//     offsets {0,1024,2048,3072}B; 1-deep prefetch double-buffer.
//   - L2 weight traffic unchanged (1x/block/layer = 1.07GB total).

#define HID 256
#define TM  32

typedef _Float16 half8 __attribute__((ext_vector_type(8)));
typedef _Float16 half4 __attribute__((ext_vector_type(4)));
typedef float    f32x4 __attribute__((ext_vector_type(4)));

#define MFMA16 __builtin_amdgcn_mfma_f32_16x16x32_f16

__device__ __forceinline__ float fast_tanh(float z) {
    // tanh(z) = 1 - 2/(exp(2z)+1); saturates correctly at +-inf
    const float e = __expf(2.0f * z);
#if __has_builtin(__builtin_amdgcn_rcpf)
    const float r = __builtin_amdgcn_rcpf(e + 1.0f);
#else
    const float r = 1.0f / (e + 1.0f);
#endif
    return fmaf(-2.0f, r, 1.0f);
}

// Pack W2/W3 (fp32 [256][256], row=k, col=n) into MFMA A-fragment order for W^T,
// fp16 (hi) only.  NEW layout: elem = ((kc*16 + strip)*64 + lane)*8 + j, so a
// wave's 4 strips per kc are contiguous (imm-offset addressable).
// frag value (kc, strip, lane, j) = W[kc*32 + (lane>>4)*8 + j][strip*16 + (lane&15)]
// ws layout (f16 elems): W2 @ 0, W3 @ 65536.  (256KB total)
__global__ __launch_bounds__(256) void prep_w(const float* __restrict__ W2,
                                              const float* __restrict__ W3,
                                              _Float16* __restrict__ wsf) {
    const int t = blockIdx.x * 256 + threadIdx.x;     // 0..16383
    const float* __restrict__ W = (t >> 13) ? W3 : W2;
    _Float16* dst = wsf + (size_t)(t >> 13) * 65536;
    const int r     = t & 8191;
    const int kc    = r >> 10;          // 0..7
    const int strip = (r >> 6) & 15;    // 0..15
    const int lane  = r & 63;
    const int row   = kc * 32 + ((lane >> 4) << 3);
    const int col   = strip * 16 + (lane & 15);
    half8 vh;
    #pragma unroll
    for (int j = 0; j < 8; ++j)
        vh[j] = (_Float16)W[(size_t)(row + j) * HID + col];
    *(half8*)&dst[(size_t)r * 8] = vh;
}

__global__ __launch_bounds__(256, 2) void pinn_mfma(
    const float* __restrict__ x,
    const float* __restrict__ W1, const float* __restrict__ b1,
    const float* __restrict__ b2, const float* __restrict__ b3,
    const float* __restrict__ W4, const float* __restrict__ b4,
    const _Float16* __restrict__ wsf,
    float* __restrict__ out, int B)
{
    // A-tile: 3 streams x 32 rows x 256 elems fp16, 16B-granule XOR-swizzle:
    // elem(s,row,e) stored at s*8192 + row*256 + (((e>>3) ^ (row&7))<<3) + (e&7)
    __shared__ __align__(16) _Float16 Ahi[3 * 32 * 256];   // 48 KB
    __shared__ float psumW[4][3][TM];                      // 1.5 KB

    const int tid  = threadIdx.x;
    const int s0   = blockIdx.x * TM;
    const int lane = tid & 63;
    const int wave = tid >> 6;          // 0..3

    // ---------- Layer 1: thread owns sample m, 32 consecutive units ----------
    // m mapped so m&7 == tid&7 (conflict-free swizzled writes in 8-lane groups)
    {
        const int m  = (tid & 7) | (((tid >> 3) & 3) << 3);   // 0..31
        const int k0 = (tid >> 5) << 5;                       // 0,32,...,224
        const float2 xv = *(const float2*)&x[(size_t)(s0 + m) * 2];
        const float x0 = xv.x, x1 = xv.y;
        half8 vh[3][4];
        #pragma unroll
        for (int q = 0; q < 4; ++q) {
            #pragma unroll
            for (int h = 0; h < 2; ++h) {
                const int n = k0 + q * 8 + h * 4;
                const f32x4 w0 = *(const f32x4*)&W1[n];
                const f32x4 w1 = *(const f32x4*)&W1[HID + n];
                const f32x4 bb = *(const f32x4*)&b1[n];
                #pragma unroll
                for (int r = 0; r < 4; ++r) {
                    const float z  = fmaf(x0, w0[r], fmaf(x1, w1[r], bb[r]));
                    const float a  = fast_tanh(z);
                    const float sN = 1.0f - a * a;
                    const float ad  = sN * w0[r];
                    const float add = -2.0f * a * ad * w0[r];
                    vh[0][q][h * 4 + r] = (_Float16)a;
                    vh[1][q][h * 4 + r] = (_Float16)ad;
                    vh[2][q][h * 4 + r] = (_Float16)add;
                }
            }
        }
        const int rkm = m & 7;
        const int g0  = k0 >> 3;          // granule base 4*(tid>>5)
        #pragma unroll
        for (int s = 0; s < 3; ++s)
            #pragma unroll
            for (int q = 0; q < 4; ++q)
                *(half8*)&Ahi[s * 8192 + m * 256 + (((g0 + q) ^ rkm) << 3)] = vh[s][q];
    }
    __syncthreads();

    const int ml = lane & 15;            // MFMA B/D col = sample (within 16-tile)
    const int hi = lane >> 4;            // 0..3
    const int rk = ml & 7;               // swizzle key (= row&7 for any mt)
    const int u4 = hi << 2;              // D-row sub-offset (unit)
    const _Float16* __restrict__ Arow = &Ahi[ml * 256];

    #pragma unroll 1
    for (int layer = 0; layer < 2; ++layer) {
        // per-wave weight base: + kc*8192 + nt*512 elems
        const _Float16* __restrict__ Wl =
            wsf + ((size_t)layer << 16) + (wave << 11) + (lane << 3);

        f32x4 acc[3][4][2];              // [stream][nt][mt]
        #pragma unroll
        for (int s = 0; s < 3; ++s)
            #pragma unroll
            for (int nt = 0; nt < 4; ++nt)
                #pragma unroll
                for (int mt = 0; mt < 2; ++mt)
                    acc[s][nt][mt] = (f32x4){0.f, 0.f, 0.f, 0.f};

        half8 wcur[4];
        #pragma unroll
        for (int nt = 0; nt < 4; ++nt)
            wcur[nt] = *(const half8*)&Wl[nt << 9];

        #pragma unroll 1
        for (int kc = 0; kc < 8; ++kc) {
            // prefetch next kc's weight frags (kc=7 reloads itself; L2-hot, safe)
            const int kn = (kc < 7) ? kc + 1 : 7;
            const _Float16* __restrict__ Wk = Wl + (kn << 13);
            half8 wnxt[4];
            #pragma unroll
            for (int nt = 0; nt < 4; ++nt)
                wnxt[nt] = *(const half8*)&Wk[nt << 9];

            // A fragments: one vaddr + imm offsets (s*8192 + mt*4096 elems)
            const _Float16* __restrict__ Ap =
                Arow + ((((kc << 2) | hi) ^ rk) << 3);
            half8 af[3][2];
            #pragma unroll
            for (int s = 0; s < 3; ++s)
                #pragma unroll
                for (int mt = 0; mt < 2; ++mt)
                    af[s][mt] = *(const half8*)&Ap[s * 8192 + mt * 4096];

            #pragma unroll
            for (int nt = 0; nt < 4; ++nt)
                #pragma unroll
                for (int mt = 0; mt < 2; ++mt) {
                    acc[0][nt][mt] = MFMA16(wcur[nt], af[0][mt], acc[0][nt][mt], 0, 0, 0);
                    acc[1][nt][mt] = MFMA16(wcur[nt], af[1][mt], acc[1][nt][mt], 0, 0, 0);
                    acc[2][nt][mt] = MFMA16(wcur[nt], af[2][mt], acc[2][nt][mt], 0, 0, 0);
                }
            #pragma unroll
            for (int nt = 0; nt < 4; ++nt) wcur[nt] = wnxt[nt];
        }

        if (layer == 0) {
            __syncthreads();   // all waves done reading A before overwrite
            // ----- layer-2 epilogue: tanh chain, quantize fp16, swizzled LDS write -----
            #pragma unroll
            for (int nt = 0; nt < 4; ++nt) {
                const int ub  = (wave << 6) + (nt << 4) + u4;   // 4 consecutive units
                const f32x4 bb = *(const f32x4*)&b2[ub];
                const int gsw = (((ub >> 3) ^ rk) << 3) + (u4 & 4);
                #pragma unroll
                for (int mt = 0; mt < 2; ++mt) {
                    half4 hv[3];
                    #pragma unroll
                    for (int r = 0; r < 4; ++r) {
                        const float z   = acc[0][nt][mt][r] + bb[r];
                        const float a   = fast_tanh(z);
                        const float sN  = 1.0f - a * a;
                        const float zd  = acc[1][nt][mt][r];
                        const float zdd = acc[2][nt][mt][r];
                        const float ad  = sN * zd;
                        const float add = fmaf(sN, zdd, -2.0f * a * ad * zd);
                        hv[0][r] = (_Float16)a;
                        hv[1][r] = (_Float16)ad;
                        hv[2][r] = (_Float16)add;
                    }
                    const int base = (mt * 16 + ml) * 256 + gsw;
                    *(half4*)&Ahi[base]         = hv[0];
                    *(half4*)&Ahi[8192  + base] = hv[1];
                    *(half4*)&Ahi[16384 + base] = hv[2];
                }
            }
            __syncthreads();
        } else {
            // ----- layer-3 epilogue fused with W4 dot: all in registers (fp32) -----
            float pd[3][2] = {{0.f, 0.f}, {0.f, 0.f}, {0.f, 0.f}};
            #pragma unroll
            for (int nt = 0; nt < 4; ++nt) {
                const int ub = (wave << 6) + (nt << 4) + u4;
                const f32x4 bb = *(const f32x4*)&b3[ub];
                const f32x4 w4 = *(const f32x4*)&W4[ub];
                #pragma unroll
                for (int mt = 0; mt < 2; ++mt) {
                    #pragma unroll
                    for (int r = 0; r < 4; ++r) {
                        const float z   = acc[0][nt][mt][r] + bb[r];
                        const float a   = fast_tanh(z);
                        const float sN  = 1.0f - a * a;
                        const float zd  = acc[1][nt][mt][r];
                        const float zdd = acc[2][nt][mt][r];
                        const float ad  = sN * zd;
                        const float add = fmaf(sN, zdd, -2.0f * a * ad * zd);
                        pd[0][mt] = fmaf(a,   w4[r], pd[0][mt]);
                        pd[1][mt] = fmaf(ad,  w4[r], pd[1][mt]);
                        pd[2][mt] = fmaf(add, w4[r], pd[2][mt]);
                    }
                }
            }
            // butterfly over lanes {ml, ml+16, ml+32, ml+48}
            #pragma unroll
            for (int s = 0; s < 3; ++s)
                #pragma unroll
                for (int mt = 0; mt < 2; ++mt) {
                    pd[s][mt] += __shfl_xor(pd[s][mt], 16, 64);
                    pd[s][mt] += __shfl_xor(pd[s][mt], 32, 64);
                }
            if (lane < 16) {
                #pragma unroll
                for (int s = 0; s < 3; ++s) {
                    psumW[wave][s][lane]      = pd[s][0];
                    psumW[wave][s][16 + lane] = pd[s][1];
                }
            }
        }
    }
    __syncthreads();

    if (tid < 96) {
        const int s = tid >> 5;          // 0:u 1:du 2:d2u
        const int m = tid & 31;
        const float v = psumW[0][s][m] + psumW[1][s][m]
                      + psumW[2][s][m] + psumW[3][s][m]
                      + ((s == 0) ? b4[0] : 0.0f);
        out[(size_t)s * B + s0 + m] = v;
    }
}

extern "C" void kernel_launch(void* const* d_in, const int* in_sizes, int n_in,
                              void* d_out, int out_size, void* d_ws, size_t ws_size,
                              hipStream_t stream) {
    const float* x  = (const float*)d_in[0];
    const float* W1 = (const float*)d_in[1];
    const float* b1 = (const float*)d_in[2];
    const float* W2 = (const float*)d_in[3];
    const float* b2 = (const float*)d_in[4];
    const float* W3 = (const float*)d_in[5];
    const float* b3 = (const float*)d_in[6];
    const float* W4 = (const float*)d_in[7];
    const float* b4 = (const float*)d_in[8];
    float* out = (float*)d_out;

    const int B = in_sizes[0] / 2;      // x is (B, 2)

    prep_w<<<64, 256, 0, stream>>>(W2, W3, (_Float16*)d_ws);
    pinn_mfma<<<B / TM, 256, 0, stream>>>(x, W1, b1, b2, b3, W4, b4,
                                          (const _Float16*)d_ws, out, B);
}